// Round 6
// baseline (3096.807 us; speedup 1.0000x reference)
//
#include <hip/hip_runtime.h>

#define XD    64      // x_dim
#define HID   256     // hidden
#define G4    1024    // 4*hidden
#define TLEN  2048
#define BATCH 64
#define NPART 8       // blocks per chain
#define UPB   32      // hidden units per part
#define TSTRIDE 16    // ints between chains' handshake-token lines (64B)

typedef unsigned int uint;

__device__ __forceinline__ float sigmf(float x) {
    return 1.0f / (1.0f + __expf(-x));
}
// tanh(x) = 1 - 2/(exp(2x)+1); __expf saturation gives correct +/-1 tails
__device__ __forceinline__ float tanhfast(float x) {
    return 1.0f - 2.0f / (1.0f + __expf(2.0f * x));
}

// ---- fused (h, stamp) 8-byte pair transport ----------------------------
// fast path (parts verified same-XCD): sc0 = bypass CU L1, coherent at the
// shared per-XCD L2. nt: never allocate in L1 so polls can't go stale.
__device__ __forceinline__ uint2 ld_pair_sc0(const uint2* p) {
    uint2 r;
    asm volatile("global_load_dwordx2 %0, %1, off sc0 nt\n\ts_waitcnt vmcnt(0)"
                 : "=v"(r) : "v"(p) : "memory");
    return r;
}
__device__ __forceinline__ void st_pair_sc0(uint2* p, uint2 v) {
    asm volatile("global_store_dwordx2 %0, %1, off sc0" :: "v"(p), "v"(v) : "memory");
}
// slow path (parts on different XCDs): device-scope 8B atomics via LLC.
__device__ __forceinline__ uint2 ld_pair_dev(const uint2* p) {
    unsigned long long u = __hip_atomic_load((const unsigned long long*)p,
                                             __ATOMIC_RELAXED, __HIP_MEMORY_SCOPE_AGENT);
    uint2 r; r.x = (uint)(u & 0xffffffffu); r.y = (uint)(u >> 32); return r;
}
__device__ __forceinline__ void st_pair_dev(uint2* p, uint2 v) {
    unsigned long long u = ((unsigned long long)v.y << 32) | (unsigned long long)v.x;
    __hip_atomic_store((unsigned long long*)p, u, __ATOMIC_RELAXED, __HIP_MEMORY_SCOPE_AGENT);
}

// Zero pair stamps (both buffers) + handshake tokens. ws is re-poisoned to
// 0xAA before every timed call, so this must run every launch.
__global__ void init_ws(unsigned long long* __restrict__ pairs, int* __restrict__ tok) {
    const int i = blockIdx.x * 256 + threadIdx.x;       // 64 blocks x 256 thr
    pairs[i] = 0ULL;                                    // buffer 0
    pairs[BATCH * HID + i] = 0ULL;                      // buffer 1
    if (threadIdx.x < TSTRIDE) tok[blockIdx.x * TSTRIDE + threadIdx.x] = 0;
}

// 512 blocks = 64 chains x 8 parts, 256 threads, 2 blocks/CU.
// Chain-major decode (r3-proven): chain = blk&63, part = blk>>6 -> all parts
// share blk%8 -> same XCD under round-robin dispatch (runtime handshake
// verifies; device-scope fallback if not).
//
// NEW vs r3: WAVE-LOCAL COLUMNS. Wave w owns units 8w..8w+7 with all 4 gates.
// Lane = s*8 + cq: slice s = lane>>3 covers operand elems [40s,40s+40); quad
// cq = lane&7 selects unit u = 8w+cq; acc.xyzw = gates i,f,g,o of unit u.
// Full z materializes with 3 intra-wave shfl_xor (8,16,32):
//   - no cross-wave zp array, NO barrier C
//   - gates run in all 4 waves concurrently (lanes 0..7 each)
//   - publish issues from 4 waves in parallel
// vec double-buffered by t&1 -> the stage->read barrier is the ONLY
// __syncthreads per step (buf t reads never alias buf t+1 writes; barrier
// #(t+1) fences the t+2 reuse of buf t).
__global__ __launch_bounds__(256, 2)
void lstm_par(const float* __restrict__ x,     // (B, T, 64)
              const float* __restrict__ wih,   // (1024, 64) row-major
              const float* __restrict__ whh,   // (1024, 256) row-major
              const float* __restrict__ bias,  // (1024)
              float* __restrict__ out,         // (B, T, 256)
              uint2* __restrict__ pairs,       // (2, B, 256) {h_bits, stamp}
              int* __restrict__ tok)           // (B, TSTRIDE) handshake tokens
{
    const int b    = blockIdx.x & 63;          // chain
    const int part = blockIdx.x >> 6;          // part
    const int tid  = threadIdx.x;
    const int lane = tid & 63;
    const int wv   = tid >> 6;                 // wave 0..3
    const int s    = lane >> 3;                // operand slice 0..7 (40 elems)
    const int cq   = lane & 7;                 // unit-within-wave
    const int u    = 8 * wv + cq;              // unit 0..31 of this part

    __shared__ __align__(16) float vecb[2][XD + HID]; // double-buffered operand
    __shared__ int fastsh;

    // ---- one-time: transposed weights + bias into registers ----
    // w4[e].{x,y,z,w} = W[gate i,f,g,o of unit u][40s + e],  W = [wih | whh]
    float4 w4[40];
    float4 b4;
    {
        int jr[4];
        #pragma unroll
        for (int q = 0; q < 4; ++q) jr[q] = q * 256 + part * UPB + u;
        b4 = make_float4(bias[jr[0]], bias[jr[1]], bias[jr[2]], bias[jr[3]]);
        #pragma unroll
        for (int e = 0; e < 40; ++e) {
            const int ge = s * 40 + e;                      // 0..319
            float v0, v1, v2, v3;
            if (ge < XD) {
                v0 = wih[jr[0] * XD + ge]; v1 = wih[jr[1] * XD + ge];
                v2 = wih[jr[2] * XD + ge]; v3 = wih[jr[3] * XD + ge];
            } else {
                const int he = ge - XD;
                v0 = whh[jr[0] * HID + he]; v1 = whh[jr[1] * HID + he];
                v2 = whh[jr[2] * HID + he]; v3 = whh[jr[3] * HID + he];
            }
            w4[e] = make_float4(v0, v1, v2, v3);
        }
    }

    // ---- one-time XCD co-location handshake (device-scope, reliable) ----
    {
        int xcc;
        asm volatile("s_getreg_b32 %0, hwreg(HW_REG_XCC_ID)" : "=s"(xcc));
        xcc &= 15;
        int* tb = tok + b * TSTRIDE;
        if (tid == 0)
            __hip_atomic_store(tb + part, 256 + xcc, __ATOMIC_RELEASE,
                               __HIP_MEMORY_SCOPE_AGENT);
        if (tid < 64) {
            const int ln = tid & 7;            // 64 lanes cover 8 tokens
            int v = 0, guard = 0;
            for (;;) {
                v = __hip_atomic_load(tb + ln, __ATOMIC_RELAXED,
                                      __HIP_MEMORY_SCOPE_AGENT);
                if (__all(v >= 256)) break;
                __builtin_amdgcn_s_sleep(2);
                if (++guard > 200000) break;   // catastrophe-only
            }
            const int ok = __all(v >= 256);
            const int v0 = __shfl(v, 0);
            const int eq = (ok && __all(v == v0)) ? 1 : 0;
            if (tid == 0) fastsh = eq;
        }
        __syncthreads();
    }
    const bool fast = (fastsh != 0);

    uint2* __restrict__ pb0 = pairs + (size_t)b * HID;            // buffer 0
    uint2* __restrict__ pb1 = pairs + (size_t)(BATCH + b) * HID;  // buffer 1
    const float* __restrict__ xb = x + (size_t)b * TLEN * XD;
    float* __restrict__ ob = out + (size_t)b * TLEN * HID;

    float cst = 0.0f;                 // lanes 0..7 of each wave own unit u's cell
    float xreg = (tid < XD) ? xb[tid] : 0.0f;   // x_0 prefetch

    for (int t = 0; t < TLEN; ++t) {
        float* __restrict__ vec = vecb[t & 1];

        // ---- gather h_{t-1}: each thread polls ITS fused pair (stamp rides
        // with the data: one L2 leg) then stages into this step's vec buffer.
        if (t > 0) {
            const uint2* src = ((t & 1) ? pb0 : pb1) + tid;  // buf (t-1)&1
            uint2 pr;
            int it = 0;
            for (;;) {
                pr = (fast && it < 4096) ? ld_pair_sc0(src) : ld_pair_dev(src);
                if (pr.y == (uint)t) break;   // exact-match: deadlock (visible
                __builtin_amdgcn_s_sleep(1);  // failure) over silent staleness
                if (++it > 100000) break;     // hang-guard: corrupt, don't hang
            }
            vec[XD + tid] = __uint_as_float(pr.x);
        } else {
            vec[XD + tid] = 0.0f;             // h_{-1} = 0
        }
        if (tid < XD) vec[tid] = xreg;
        __syncthreads();  // ONLY barrier per step: stage -> read

        // prefetch next x (latency overlapped by compute + next poll)
        if (t + 1 < TLEN && tid < XD) xreg = xb[(size_t)(t + 1) * XD + tid];

        // ---- 40-elem slice x 4 gate-columns of unit u: 10 ds_read_b128,
        // 160 FMA (acc.xyzw = gates i,f,g,o) ----
        float4 acc = make_float4(0.f, 0.f, 0.f, 0.f);
        const float4* vb = (const float4*)(vec + 40 * s);
        #pragma unroll
        for (int i = 0; i < 10; ++i) {
            const float4 v = vb[i];
            #define FMA1(R, VE)                              \
                acc.x = fmaf(w4[4*i + R].x, (VE), acc.x);    \
                acc.y = fmaf(w4[4*i + R].y, (VE), acc.y);    \
                acc.z = fmaf(w4[4*i + R].z, (VE), acc.z);    \
                acc.w = fmaf(w4[4*i + R].w, (VE), acc.w);
            FMA1(0, v.x) FMA1(1, v.y) FMA1(2, v.z) FMA1(3, v.w)
            #undef FMA1
        }
        // ---- intra-wave slice reduction: butterfly over s (lanes s*8+cq) ----
        acc.x += __shfl_xor(acc.x, 8);
        acc.y += __shfl_xor(acc.y, 8);
        acc.z += __shfl_xor(acc.z, 8);
        acc.w += __shfl_xor(acc.w, 8);
        acc.x += __shfl_xor(acc.x, 16);
        acc.y += __shfl_xor(acc.y, 16);
        acc.z += __shfl_xor(acc.z, 16);
        acc.w += __shfl_xor(acc.w, 16);
        acc.x += __shfl_xor(acc.x, 32);
        acc.y += __shfl_xor(acc.y, 32);
        acc.z += __shfl_xor(acc.z, 32);
        acc.w += __shfl_xor(acc.w, 32);

        // ---- gates + state + publish: lanes 0..7 of EVERY wave (unit u) ----
        if (lane < 8) {
            const float ig = sigmf(acc.x + b4.x);
            const float fg = sigmf(acc.y + b4.y);
            const float gg = tanhfast(acc.z + b4.z);
            const float og = sigmf(acc.w + b4.w);
            cst = fg * cst + ig * gg;
            const float h = og * tanhfast(cst);
            // fused publish: stamp travels WITH the value (single 8B store)
            uint2 pv; pv.x = __float_as_uint(h); pv.y = (uint)(t + 1);
            uint2* dst = ((t & 1) ? pb1 : pb0) + part * UPB + u;
            if (fast) st_pair_sc0(dst, pv);
            else      st_pair_dev(dst, pv);
            // output store AFTER the publish: off the inter-part critical path
            ob[(size_t)t * HID + part * UPB + u] = h;
        }
    }
}

extern "C" void kernel_launch(void* const* d_in, const int* in_sizes, int n_in,
                              void* d_out, int out_size, void* d_ws, size_t ws_size,
                              hipStream_t stream) {
    const float* x    = (const float*)d_in[0];
    const float* wih  = (const float*)d_in[1];
    const float* whh  = (const float*)d_in[2];
    const float* bias = (const float*)d_in[3];
    float* out = (float*)d_out;

    uint2* pairs = (uint2*)d_ws;  // 2*64*256 pairs = 256 KB
    int*   tok   = (int*)((char*)d_ws + (size_t)2 * BATCH * HID * sizeof(uint2)); // 4 KB

    hipLaunchKernelGGL(init_ws, dim3(BATCH), dim3(256), 0, stream,
                       (unsigned long long*)d_ws, tok);
    hipLaunchKernelGGL(lstm_par, dim3(BATCH * NPART), dim3(256), 0, stream,
                       x, wih, whh, bias, out, pairs, tok);
}

// Round 7
// 2737.374 us; speedup vs baseline: 1.1313x; 1.1313x over previous
//
#include <hip/hip_runtime.h>

#define XD    64      // x_dim
#define HID   256     // hidden
#define G4    1024    // 4*hidden
#define TLEN  2048
#define BATCH 64
#define NPART 8       // blocks per chain
#define UPB   32      // hidden units per part
#define CPB   128     // gate columns per part (4 gates x 32 units)
#define TSTRIDE 16    // ints between chains' handshake-token lines (64B)

typedef unsigned int uint;

__device__ __forceinline__ float sigmf(float x) {
    return 1.0f / (1.0f + __expf(-x));
}
// tanh(x) = 1 - 2/(exp(2x)+1); __expf saturation gives correct +/-1 tails
__device__ __forceinline__ float tanhfast(float x) {
    return 1.0f - 2.0f / (1.0f + __expf(2.0f * x));
}

// ---- fused (h, stamp) 8-byte pair transport ----------------------------
// fast path (parts verified same-XCD): sc0 = bypass CU L1, coherent at the
// shared per-XCD L2. nt: never allocate in L1 so polls can't go stale.
__device__ __forceinline__ void ld_pair_issue(uint2& r, const uint2* p) {
    // ISSUE ONLY -- no waitcnt. Caller manages vmcnt explicitly.
    asm volatile("global_load_dwordx2 %0, %1, off sc0 nt"
                 : "=v"(r) : "v"(p) : "memory");
}
__device__ __forceinline__ void wait_vm1() {
    asm volatile("s_waitcnt vmcnt(1)" ::: "memory");
    __builtin_amdgcn_sched_barrier(0);   // rule #18: fence reg readers
}
__device__ __forceinline__ void wait_vm0() {
    asm volatile("s_waitcnt vmcnt(0)" ::: "memory");
    __builtin_amdgcn_sched_barrier(0);
}
__device__ __forceinline__ void st_pair_sc0(uint2* p, uint2 v) {
    asm volatile("global_store_dwordx2 %0, %1, off sc0" :: "v"(p), "v"(v) : "memory");
}
// slow path (parts on different XCDs): device-scope 8B atomics via LLC.
__device__ __forceinline__ uint2 ld_pair_dev(const uint2* p) {
    unsigned long long u = __hip_atomic_load((const unsigned long long*)p,
                                             __ATOMIC_RELAXED, __HIP_MEMORY_SCOPE_AGENT);
    uint2 r; r.x = (uint)(u & 0xffffffffu); r.y = (uint)(u >> 32); return r;
}
__device__ __forceinline__ void st_pair_dev(uint2* p, uint2 v) {
    unsigned long long u = ((unsigned long long)v.y << 32) | (unsigned long long)v.x;
    __hip_atomic_store((unsigned long long*)p, u, __ATOMIC_RELAXED, __HIP_MEMORY_SCOPE_AGENT);
}

// Zero pair stamps (both buffers) + handshake tokens. ws is re-poisoned to
// 0xAA before every timed call, so this must run every launch.
__global__ void init_ws(unsigned long long* __restrict__ pairs, int* __restrict__ tok) {
    const int i = blockIdx.x * 256 + threadIdx.x;       // 64 blocks x 256 thr
    pairs[i] = 0ULL;                                    // buffer 0
    pairs[BATCH * HID + i] = 0ULL;                      // buffer 1
    if (threadIdx.x < TSTRIDE) tok[blockIdx.x * TSTRIDE + threadIdx.x] = 0;
}

// 512 blocks = 64 chains x 8 parts, 256 threads, 2 blocks/CU (r3 structure,
// best measured = 2758us). Chain-major decode: chain = blk&63, part = blk>>6
// -> all parts share blk%8 -> same XCD under round-robin dispatch (runtime
// handshake verifies; device-scope fallback if not).
//
// NEW vs r3 (single change): PIPELINED POLL. The old poll serialized
// load(~250cy) -> check -> sleep(64cy) per sample: ~300cy sampling period,
// costing 1-3 periods of detect lag per step per wave (the dominant hidden
// serial term). Now 2 same-address sc0 loads stay in flight; s_waitcnt
// vmcnt(1) + check oldest + reissue alternates at ~latency/2 period (~100cy).
// Safe because a pair is stable-once-published within a step: the t+2
// overwrite requires the producer to pass step t+1, which requires THIS
// block's stamp t+1, which is published only after this poll completes.
__global__ __launch_bounds__(256, 2)
void lstm_par(const float* __restrict__ x,     // (B, T, 64)
              const float* __restrict__ wih,   // (1024, 64) row-major
              const float* __restrict__ whh,   // (1024, 256) row-major
              const float* __restrict__ bias,  // (1024)
              float* __restrict__ out,         // (B, T, 256)
              uint2* __restrict__ pairs,       // (2, B, 256) {h_bits, stamp}
              int* __restrict__ tok)           // (B, TSTRIDE) handshake tokens
{
    const int b    = blockIdx.x & 63;          // chain
    const int part = blockIdx.x >> 6;          // part
    const int tid  = threadIdx.x;
    const int lane = tid & 63;
    const int wv   = tid >> 6;                 // wave 0..3
    const int s    = tid >> 5;                 // operand slice 0..7 (40 elems)
    const int cq   = tid & 31;                 // column quad: cols 4cq..4cq+3

    __shared__ __align__(16) float vec[XD + HID]; // [x_t | h_{t-1}]
    __shared__ __align__(16) float zp[4][CPB];    // per-wave z partials
    __shared__ int fastsh;

    // ---- one-time: transposed weights into registers ----
    // w4[e] = weights of the thread's 4 columns at combined-element 40s+e.
    float4 w4[40];
    {
        int jr[4];
        #pragma unroll
        for (int k = 0; k < 4; ++k) {
            const int c = 4 * cq + k;                       // col within part
            jr[k] = (c >> 5) * 256 + part * UPB + (c & 31); // global gate row
        }
        #pragma unroll
        for (int e = 0; e < 40; ++e) {
            const int ge = s * 40 + e;                      // 0..319
            float v0, v1, v2, v3;
            if (ge < XD) {
                v0 = wih[jr[0] * XD + ge]; v1 = wih[jr[1] * XD + ge];
                v2 = wih[jr[2] * XD + ge]; v3 = wih[jr[3] * XD + ge];
            } else {
                const int he = ge - XD;
                v0 = whh[jr[0] * HID + he]; v1 = whh[jr[1] * HID + he];
                v2 = whh[jr[2] * HID + he]; v3 = whh[jr[3] * HID + he];
            }
            w4[e] = make_float4(v0, v1, v2, v3);
        }
    }
    // gate-wave bias preload (threads 0..31: unit u = tid)
    float bi = 0.f, bf = 0.f, bg = 0.f, bo = 0.f;
    if (tid < UPB) {
        const int gj = part * UPB + tid;
        bi = bias[gj]; bf = bias[256 + gj]; bg = bias[512 + gj]; bo = bias[768 + gj];
    }

    // ---- one-time XCD co-location handshake (device-scope, reliable) ----
    {
        int xcc;
        asm volatile("s_getreg_b32 %0, hwreg(HW_REG_XCC_ID)" : "=s"(xcc));
        xcc &= 15;
        int* tb = tok + b * TSTRIDE;
        if (tid == 0)
            __hip_atomic_store(tb + part, 256 + xcc, __ATOMIC_RELEASE,
                               __HIP_MEMORY_SCOPE_AGENT);
        if (tid < 64) {
            const int ln = tid & 7;            // 64 lanes cover 8 tokens
            int v = 0, guard = 0;
            for (;;) {
                v = __hip_atomic_load(tb + ln, __ATOMIC_RELAXED,
                                      __HIP_MEMORY_SCOPE_AGENT);
                if (__all(v >= 256)) break;
                __builtin_amdgcn_s_sleep(2);
                if (++guard > 200000) break;   // catastrophe-only
            }
            const int ok = __all(v >= 256);
            const int v0 = __shfl(v, 0);
            const int eq = (ok && __all(v == v0)) ? 1 : 0;
            if (tid == 0) fastsh = eq;
        }
        __syncthreads();
    }
    const bool fast = (fastsh != 0);

    uint2* __restrict__ pb0 = pairs + (size_t)b * HID;            // buffer 0
    uint2* __restrict__ pb1 = pairs + (size_t)(BATCH + b) * HID;  // buffer 1
    const float* __restrict__ xb = x + (size_t)b * TLEN * XD;
    float* __restrict__ ob = out + (size_t)b * TLEN * HID;

    float cst = 0.0f;                     // thread tid<32 owns cell of unit tid
    float xreg = (tid < XD) ? xb[tid] : 0.0f;   // x_0 prefetch

    for (int t = 0; t < TLEN; ++t) {
        // ---- gather h_{t-1}: pipelined poll on this thread's fused pair ----
        if (t > 0) {
            const uint2* src = ((t & 1) ? pb0 : pb1) + tid;  // buf (t-1)&1
            uint2 res;
            if (fast) {
                uint2 va, vb;
                ld_pair_issue(va, src);       // 2 in flight, same address
                ld_pair_issue(vb, src);
                int it = 0;
                for (;;) {
                    wait_vm1();               // oldest (va) returned
                    if (__all(va.y == (uint)t)) { res = va; break; }
                    ld_pair_issue(va, src);   // reissue as newest
                    wait_vm1();               // oldest (vb) returned
                    if (__all(vb.y == (uint)t)) { res = vb; break; }
                    ld_pair_issue(vb, src);
                    if (++it > 50000) { res = vb; break; }  // hang-guard
                }
                // drain the 1-2 stale in-flight loads before their target
                // registers (possibly aliased with res) are read/reused.
                // Post-drain values still carry stamp t (stable within step).
                wait_vm0();
            } else {
                // device-scope fallback: original r3 sleep-poll protocol
                uint2 pr; int it = 0;
                for (;;) {
                    pr = ld_pair_dev(src);
                    if (pr.y == (uint)t) break;
                    __builtin_amdgcn_s_sleep(1);
                    if (++it > 100000) break;  // hang-guard
                }
                res = pr;
            }
            vec[XD + tid] = __uint_as_float(res.x);
        } else {
            vec[XD + tid] = 0.0f;             // h_{-1} = 0
        }
        if (tid < XD) vec[tid] = xreg;
        __syncthreads(); // (B) -- also protects vec/zp from next-step overwrite

        // prefetch next x (latency overlapped by compute + next poll)
        if (t + 1 < TLEN && tid < XD) xreg = xb[(size_t)(t + 1) * XD + tid];

        // ---- 40-element slice x 4 columns: 10 ds_read_b128, 160 FMA ----
        float4 acc = make_float4(0.f, 0.f, 0.f, 0.f);
        const float4* vb4 = (const float4*)(vec + 40 * s);
        #pragma unroll
        for (int i = 0; i < 10; ++i) {
            const float4 v = vb4[i];
            #define FMA1(R, VE)                              \
                acc.x = fmaf(w4[4*i + R].x, (VE), acc.x);    \
                acc.y = fmaf(w4[4*i + R].y, (VE), acc.y);    \
                acc.z = fmaf(w4[4*i + R].z, (VE), acc.z);    \
                acc.w = fmaf(w4[4*i + R].w, (VE), acc.w);
            FMA1(0, v.x) FMA1(1, v.y) FMA1(2, v.z) FMA1(3, v.w)
            #undef FMA1
        }
        // combine slice pairs (lane l <-> l^32 hold slices 2wv, 2wv+1)
        acc.x += __shfl_xor(acc.x, 32);
        acc.y += __shfl_xor(acc.y, 32);
        acc.z += __shfl_xor(acc.z, 32);
        acc.w += __shfl_xor(acc.w, 32);
        if (lane < 32) *(float4*)(&zp[wv][4 * lane]) = acc;
        __syncthreads(); // (C)

        // ---- gates, state update, publish (threads 0..31; all in wave 0) ----
        if (tid < UPB) {
            float zi = bi, zf = bf, zg = bg, zo = bo;
            #pragma unroll
            for (int w2 = 0; w2 < 4; ++w2) {
                zi += zp[w2][tid];            // col c = 0*32 + tid (gate i)
                zf += zp[w2][32 + tid];       // gate f
                zg += zp[w2][64 + tid];       // gate g
                zo += zp[w2][96 + tid];       // gate o
            }
            const float ig = sigmf(zi);
            const float fg = sigmf(zf);
            const float gg = tanhfast(zg);
            const float og = sigmf(zo);
            cst = fg * cst + ig * gg;
            const float h = og * tanhfast(cst);
            // fused publish: stamp travels WITH the value (single 8B store)
            uint2 pv; pv.x = __float_as_uint(h); pv.y = (uint)(t + 1);
            uint2* dst = ((t & 1) ? pb1 : pb0) + part * UPB + tid;
            if (fast) st_pair_sc0(dst, pv);
            else      st_pair_dev(dst, pv);
            // output store AFTER the publish: off the inter-part critical path
            ob[(size_t)t * HID + part * UPB + tid] = h;
        }
    }
}

extern "C" void kernel_launch(void* const* d_in, const int* in_sizes, int n_in,
                              void* d_out, int out_size, void* d_ws, size_t ws_size,
                              hipStream_t stream) {
    const float* x    = (const float*)d_in[0];
    const float* wih  = (const float*)d_in[1];
    const float* whh  = (const float*)d_in[2];
    const float* bias = (const float*)d_in[3];
    float* out = (float*)d_out;

    uint2* pairs = (uint2*)d_ws;  // 2*64*256 pairs = 256 KB
    int*   tok   = (int*)((char*)d_ws + (size_t)2 * BATCH * HID * sizeof(uint2)); // 4 KB

    hipLaunchKernelGGL(init_ws, dim3(BATCH), dim3(256), 0, stream,
                       (unsigned long long*)d_ws, tok);
    hipLaunchKernelGGL(lstm_par, dim3(BATCH * NPART), dim3(256), 0, stream,
                       x, wih, whh, bias, out, pairs, tok);
}